// Round 1
// baseline (313.911 us; speedup 1.0000x reference)
//
#include <hip/hip_runtime.h>
#include <math.h>

// SSIM-with-logits fused kernel for MI355X (gfx950).
// input:  d_in[0] = logits (16,1,1024,1024) fp32 ; d_in[1] = target, same shape
// output: d_out[0] = mean(clip(1-ssim,0,1)/2), single fp32
//
// Strategy: column-per-thread separable 11-tap Gaussian (reflect pad).
//  - block = 256 threads handles a 256(w) x 128(h) output tile; grid = 512 blocks
//  - stage 8 input rows (sigmoid applied at load) into LDS per iteration
//  - horizontal filter of 5 channels (a, b, a2, b2, ab) read from LDS
//  - vertical filter via an 11-deep per-thread register rolling window
//  - per-thread loss accumulation -> wave shuffle reduce -> one atomicAdd/block

#define H_IMG 1024
#define W_IMG 1024
#define N_IMG 16
#define TILE_W 256
#define TILE_H 128
#define PADR 5
#define STAGE_ROWS 8
#define LDS_STRIDE (TILE_W + 2 * PADR + 6)  // 272 floats per staged row

__device__ __forceinline__ int reflect_i(int i, int n) {
    i = (i < 0) ? -i : i;
    i = (i >= n) ? (2 * n - 2 - i) : i;
    return i;
}

__global__ __launch_bounds__(256, 2) void ssim_main(
    const float* __restrict__ inp, const float* __restrict__ tgt,
    float* __restrict__ out)
{
    __shared__ float a_s[STAGE_ROWS][LDS_STRIDE];
    __shared__ float b_s[STAGE_ROWS][LDS_STRIDE];
    __shared__ float red[4];

    // Normalized 1D Gaussian, WS=11, sigma=1.5 (matches kornia/jax fp32 to ~1e-7)
    constexpr float GW[11] = {
        0.00102838f, 0.00759877f, 0.03600077f, 0.10936069f, 0.21300553f,
        0.26601172f,
        0.21300553f, 0.10936069f, 0.03600077f, 0.00759877f, 0.00102838f};

    const int tid = threadIdx.x;
    const int blk = blockIdx.x;
    const int b   = blk >> 5;          // image index 0..15
    const int cx  = blk & 3;           // column tile 0..3
    const int ry  = (blk >> 2) & 7;    // row band 0..7
    const int x0  = cx * TILE_W;
    const int y0  = ry * TILE_H;

    const float* __restrict__ A = inp + (size_t)b * (H_IMG * (size_t)W_IMG);
    const float* __restrict__ B = tgt + (size_t)b * (H_IMG * (size_t)W_IMG);

    // reflected source columns for the two staging loads this thread performs
    const int c0 = reflect_i(x0 - PADR + tid, W_IMG);
    const int c1 = (tid < 2 * PADR) ? reflect_i(x0 + TILE_W - PADR + tid, W_IMG) : 0;

    float accA[11], accB[11], accAA[11], accBB[11], accAB[11];
#pragma unroll
    for (int j = 0; j < 11; ++j) {
        accA[j] = 0.f; accB[j] = 0.f; accAA[j] = 0.f; accBB[j] = 0.f; accAB[j] = 0.f;
    }

    float loss_sum = 0.0f;

    const int y_start = y0 - PADR;         // first input row (may be negative)
    const int n_rows  = TILE_H + 2 * PADR; // 138 input rows

    for (int base = 0; base < n_rows; base += STAGE_ROWS) {
        __syncthreads();  // previous iteration's LDS reads complete before overwrite
        const int nr = min(STAGE_ROWS, n_rows - base);
        for (int r = 0; r < nr; ++r) {
            const int yy = reflect_i(y_start + base + r, H_IMG);
            const float* __restrict__ ar = A + (size_t)yy * W_IMG;
            const float* __restrict__ br = B + (size_t)yy * W_IMG;
            float av = ar[c0];
            a_s[r][tid] = 1.0f / (1.0f + __expf(-av));  // sigmoid once per element
            b_s[r][tid] = br[c0];
            if (tid < 2 * PADR) {
                float av2 = ar[c1];
                a_s[r][TILE_W + tid] = 1.0f / (1.0f + __expf(-av2));
                b_s[r][TILE_W + tid] = br[c1];
            }
        }
        __syncthreads();

        for (int r = 0; r < nr; ++r) {
            // ---- horizontal 11-tap filter of 5 channels at column x0+tid ----
            float ha = 0.f, hb = 0.f, haa = 0.f, hbb = 0.f, hab = 0.f;
#pragma unroll
            for (int k = 0; k < 11; ++k) {
                const float a  = a_s[r][tid + k];
                const float bb = b_s[r][tid + k];
                const float wa = GW[k] * a;
                const float wb = GW[k] * bb;
                ha += wa;
                hb += wb;
                haa = fmaf(wa, a, haa);
                hab = fmaf(wa, bb, hab);
                hbb = fmaf(wb, bb, hbb);
            }
            // ---- vertical accumulate into rolling window ----
            // slot j holds output row (y_in - 5 + j); this row contributes W[10-j]
#pragma unroll
            for (int j = 0; j < 11; ++j) {
                const float w = GW[10 - j];
                accA[j]  = fmaf(w, ha,  accA[j]);
                accB[j]  = fmaf(w, hb,  accB[j]);
                accAA[j] = fmaf(w, haa, accAA[j]);
                accBB[j] = fmaf(w, hbb, accBB[j]);
                accAB[j] = fmaf(w, hab, accAB[j]);
            }
            const int y_in = y_start + base + r;
            if (y_in >= y0 + PADR) {  // slot 0 complete -> output row y_in-5
                const float mu1 = accA[0], mu2 = accB[0];
                const float e11 = accAA[0], e22 = accBB[0], e12 = accAB[0];
                const float mu1s = mu1 * mu1;
                const float mu2s = mu2 * mu2;
                const float mu12 = mu1 * mu2;
                const float s1  = e11 - mu1s;
                const float s2  = e22 - mu2s;
                const float s12 = e12 - mu12;
                const float C1 = 1e-4f, C2 = 9e-4f;
                const float num = (2.0f * mu12 + C1) * (2.0f * s12 + C2);
                const float den = (mu1s + mu2s + C1) * (s1 + s2 + C2);
                const float ssim = num / den;
                float l = 1.0f - ssim;
                l = fminf(fmaxf(l, 0.0f), 1.0f) * 0.5f;
                loss_sum += l;
            }
            // shift window down, clear top
#pragma unroll
            for (int j = 0; j < 10; ++j) {
                accA[j] = accA[j + 1]; accB[j] = accB[j + 1];
                accAA[j] = accAA[j + 1]; accBB[j] = accBB[j + 1];
                accAB[j] = accAB[j + 1];
            }
            accA[10] = 0.f; accB[10] = 0.f; accAA[10] = 0.f;
            accBB[10] = 0.f; accAB[10] = 0.f;
        }
    }

    // ---- reduction: wave64 shuffle -> LDS across 4 waves -> atomicAdd ----
#pragma unroll
    for (int off = 32; off > 0; off >>= 1)
        loss_sum += __shfl_down(loss_sum, off, 64);
    const int wave = tid >> 6;
    if ((tid & 63) == 0) red[wave] = loss_sum;
    __syncthreads();
    if (tid == 0) {
        const float s = red[0] + red[1] + red[2] + red[3];
        atomicAdd(out, s * (1.0f / ((float)N_IMG * H_IMG * W_IMG)));
    }
}

extern "C" void kernel_launch(void* const* d_in, const int* in_sizes, int n_in,
                              void* d_out, int out_size, void* d_ws, size_t ws_size,
                              hipStream_t stream) {
    const float* inp = (const float*)d_in[0];
    const float* tgt = (const float*)d_in[1];
    float* out = (float*)d_out;

    // d_out is poisoned 0xAA before every launch; zero it for the atomic sum.
    hipMemsetAsync(out, 0, sizeof(float), stream);

    const int grid = N_IMG * 4 * 8;  // 512 blocks
    ssim_main<<<grid, 256, 0, stream>>>(inp, tgt, out);
}